// Round 2
// baseline (273.140 us; speedup 1.0000x reference)
//
#include <hip/hip_runtime.h>

typedef unsigned long long u64;
typedef unsigned int u32;

#define FEAT_W 100
#define NANCH 9
#define NTOT 57600
#define NPAD 65536
#define PRE_NMS 6000
#define POST_NMS 300
#define NWORDS 94       // mask row stride in u64 words (6000 bits)
#define NCHUNK 24       // ceil(94/4): 4 mask words (256 boxes) per scan iteration
#define CH_STRIDE 6400
#define CHUNK 1024
#define CAP 6144

__constant__ double c_base[9][4] = {
    {-84.0, -40.0, 99.0, 55.0},    {-176.0, -88.0, 191.0, 103.0},
    {-360.0, -184.0, 375.0, 199.0},{-56.0, -56.0, 71.0, 71.0},
    {-120.0, -120.0, 135.0, 135.0},{-248.0, -248.0, 263.0, 263.0},
    {-36.0, -80.0, 51.0, 95.0},    {-80.0, -168.0, 95.0, 183.0},
    {-168.0, -344.0, 183.0, 359.0}};

struct BoxD { double x1, y1, x2, y2; };

__device__ __forceinline__ BoxD decode_box(int i, const float* __restrict__ bbox,
                                           double imw1, double imh1) {
  int pos = i / NANCH;
  int a = i - pos * NANCH;
  int h = pos / FEAT_W;
  int w = pos - h * FEAT_W;
  double ax1 = c_base[a][0] + 16.0 * (double)w;
  double ay1 = c_base[a][1] + 16.0 * (double)h;
  double ax2 = c_base[a][2] + 16.0 * (double)w;
  double ay2 = c_base[a][3] + 16.0 * (double)h;
  double wd = ax2 - ax1 + 1.0;
  double hg = ay2 - ay1 + 1.0;
  double cx = ax1 + 0.5 * wd;
  double cy = ay1 + 0.5 * hg;
  const float* bp = bbox + (size_t)(4 * a) * CH_STRIDE + pos;
  double dx = (double)bp[0];
  double dy = (double)bp[CH_STRIDE];
  double dw = (double)bp[2 * CH_STRIDE];
  double dh = (double)bp[3 * CH_STRIDE];
  double pcx = dx * wd + cx;
  double pcy = dy * hg + cy;
  double pw = exp(dw) * wd;
  double ph = exp(dh) * hg;
  BoxD b;
  b.x1 = fmin(fmax(pcx - 0.5 * pw, 0.0), imw1);
  b.y1 = fmin(fmax(pcy - 0.5 * ph, 0.0), imh1);
  b.x2 = fmin(fmax(pcx + 0.5 * pw, 0.0), imw1);
  b.y2 = fmin(fmax(pcy + 0.5 * ph, 0.0), imh1);
  return b;
}

__device__ __forceinline__ u64 score_key(int i, const float* __restrict__ cls,
                                         const float* __restrict__ bbox,
                                         double imw1, double imh1) {
  BoxD b = decode_box(i, bbox, imw1, imh1);
  bool valid = (b.x2 - b.x1 + 1.0 >= 16.0) && (b.y2 - b.y1 + 1.0 >= 16.0);
  int pos = i / NANCH;
  int a = i - pos * NANCH;
  double c0 = (double)cls[(size_t)(2 * a) * CH_STRIDE + pos];
  double c1 = (double)cls[(size_t)(2 * a + 1) * CH_STRIDE + pos];
  double m = fmax(c0, c1);
  double e0 = exp(c0 - m), e1 = exp(c1 - m);
  double s = e1 / (e0 + e1);
  double masked = valid ? s : (double)(-1e30f);
  u64 u = (u64)__double_as_longlong(masked);
  return (u >> 63) ? ~u : (u | 0x8000000000000000ULL);
}

__device__ __forceinline__ bool before(u64 ka, u32 va, u64 kb, u32 vb) {
  return (ka > kb) || (ka == kb && va < vb);
}
__device__ __forceinline__ bool comes_after(u64 ka, u32 va, u64 kb, u32 vb) {
  return (ka < kb) || (ka == kb && va > vb);
}

__device__ __forceinline__ int count_before(const u64* Sk, const u32* Sv, int n,
                                            u64 k, u32 v) {
  int lo = 0, hi = n;
  while (lo < hi) {
    int m = (lo + hi) >> 1;
    if (before(Sk[m], Sv[m], k, v)) lo = m + 1; else hi = m;
  }
  return lo;
}

// 64 blocks: compute 1024 keys, bitonic-sort in LDS (55 stages), write chunk.
__global__ __launch_bounds__(512) void k_score_sort(
    const float* __restrict__ cls, const float* __restrict__ bbox,
    const int* __restrict__ imh, const int* __restrict__ imw,
    u64* __restrict__ keys, u32* __restrict__ vals) {
  __shared__ u64 sk[CHUNK];
  __shared__ u32 sv[CHUNK];
  int base = blockIdx.x * CHUNK;
  double imh1 = (double)(imh[0] - 1);
  double imw1 = (double)(imw[0] - 1);
  for (int t = threadIdx.x; t < CHUNK; t += 512) {
    int i = base + t;
    if (i < NTOT) { sk[t] = score_key(i, cls, bbox, imw1, imh1); sv[t] = (u32)i; }
    else { sk[t] = 0ULL; sv[t] = (u32)i; }
  }
  __syncthreads();
  for (int k = 2; k <= CHUNK; k <<= 1) {
    for (int j = k >> 1; j > 0; j >>= 1) {
      int t = threadIdx.x;
      int i = ((t & ~(j - 1)) << 1) | (t & (j - 1));
      int l = i | j;
      bool up = ((i & k) == 0);
      u64 ka = sk[i], kb = sk[l];
      u32 va = sv[i], vb = sv[l];
      if (comes_after(ka, va, kb, vb) == up) { sk[i] = kb; sv[i] = vb; sk[l] = ka; sv[l] = va; }
      __syncthreads();
    }
  }
  for (int t = threadIdx.x; t < CHUNK; t += 512) { keys[base + t] = sk[t]; vals[base + t] = sv[t]; }
}

// r1: 64 lists x1024 -> 16 x4096 (A -> B), 4-way rank-merge.
__global__ void k_merge1(const u64* __restrict__ Ak, const u32* __restrict__ Av,
                         u64* __restrict__ Bk, u32* __restrict__ Bv) {
  int gtid = blockIdx.x * blockDim.x + threadIdx.x;
  if (gtid >= NPAD) return;
  int lst = gtid >> 10, pos = gtid & 1023, grp = lst >> 2;
  u64 k = Ak[gtid]; u32 v = Av[gtid];
  int rank = pos;
  int b0 = grp << 2;
  #pragma unroll
  for (int s = 0; s < 4; ++s)
    if ((b0 + s) != lst)
      rank += count_before(Ak + (size_t)(b0 + s) * 1024, Av + (size_t)(b0 + s) * 1024, 1024, k, v);
  Bk[(size_t)grp * 4096 + rank] = k;
  Bv[(size_t)grp * 4096 + rank] = v;
}

// r2: 16 lists x4096 -> 4 x6144 (B -> A), truncated.
__global__ void k_merge2(const u64* __restrict__ Bk, const u32* __restrict__ Bv,
                         u64* __restrict__ Ak, u32* __restrict__ Av) {
  int gtid = blockIdx.x * blockDim.x + threadIdx.x;
  if (gtid >= NPAD) return;
  int lst = gtid >> 12, pos = gtid & 4095, grp = lst >> 2;
  u64 k = Bk[gtid]; u32 v = Bv[gtid];
  int rank = pos;
  int b0 = grp << 2;
  #pragma unroll
  for (int s = 0; s < 4; ++s)
    if ((b0 + s) != lst)
      rank += count_before(Bk + (size_t)(b0 + s) * 4096, Bv + (size_t)(b0 + s) * 4096, 4096, k, v);
  if (rank < CAP) { Ak[(size_t)grp * CAP + rank] = k; Av[(size_t)grp * CAP + rank] = v; }
}

// r3: 4 lists x6144 -> top-6000, fused with box decode into sboxes.
__global__ void k_merge3(const u64* __restrict__ Ak, const u32* __restrict__ Av,
                         const float* __restrict__ bbox, const int* __restrict__ imh,
                         const int* __restrict__ imw, double4* __restrict__ sboxes) {
  int gtid = blockIdx.x * blockDim.x + threadIdx.x;
  if (gtid >= 4 * CAP) return;
  int lst = gtid / CAP, pos = gtid - lst * CAP;
  u64 k = Ak[gtid]; u32 v = Av[gtid];
  int rank = pos;
  #pragma unroll
  for (int s = 0; s < 4; ++s)
    if (s != lst)
      rank += count_before(Ak + (size_t)s * CAP, Av + (size_t)s * CAP, CAP, k, v);
  if (rank < PRE_NMS) {
    double imh1 = (double)(imh[0] - 1);
    double imw1 = (double)(imw[0] - 1);
    BoxD b = decode_box((int)v, bbox, imw1, imh1);
    sboxes[rank] = make_double4(b.x1, b.y1, b.x2, b.y2);
  }
}

__global__ void k_mask(const double4* __restrict__ sboxes, u64* __restrict__ mask) {
  __shared__ double4 cb[64];
  int bc = blockIdx.x, br = blockIdx.y;
  int t = threadIdx.x;
  int j0 = bc * 64;
  int jt = j0 + t;
  cb[t] = (jt < PRE_NMS) ? sboxes[jt] : make_double4(0.0, 0.0, 0.0, 0.0);
  __syncthreads();
  int i = br * 64 + t;
  if (i >= PRE_NMS) return;
  double4 rb = sboxes[i];
  double areai = (rb.z - rb.x) * (rb.w - rb.y);
  u64 bits = 0;
  int cmax = min(64, PRE_NMS - j0);
  for (int c = 0; c < cmax; ++c) {
    int j = j0 + c;
    if (j <= i) continue;
    double4 cbx = cb[c];
    double xx1 = fmax(rb.x, cbx.x), yy1 = fmax(rb.y, cbx.y);
    double xx2 = fmin(rb.z, cbx.z), yy2 = fmin(rb.w, cbx.w);
    double w = fmax(xx2 - xx1, 0.0), h = fmax(yy2 - yy1, 0.0);
    double inter = w * h;
    double areaj = (cbx.z - cbx.x) * (cbx.w - cbx.y);
    double iou = inter / (areai + areaj - inter);
    if (iou > 0.7) bits |= (1ULL << c);
  }
  mask[(size_t)i * NWORDS + bc] = bits;
}

__device__ __forceinline__ u64 valid_word(int w) {
  int base = w << 6;
  if (base + 64 <= PRE_NMS) return ~0ULL;
  if (base >= PRE_NMS) return 0ULL;
  return (1ULL << (PRE_NMS - base)) - 1ULL;
}

// Chunk-tile greedy NMS scan, single wave, no speculation.
// v3: 256-box super-chunks (4 mask words) per outer iteration -> the
// dependent-latency chain is 24 iterations instead of 94. Mask layout is the
// proven 94-word-stride one (no workspace growth); the 4 words of a group are
// read as independent scalar u64 loads (tail-guarded for the last chunk,
// which only has words 92..93). Per iteration:
//   alive[0..3] = ~OR{mask[k][4c..4c+4) : k kept} & valid
//       (<=36 independent 8B loads, one vmcnt wait)
//   intra-chunk greedy via 256x256-bit diagonal tile held in registers:
//       lane l holds rows 256c + q*64 + l (q=0..3), 4 words each
//       (prefetched one chunk ahead; 4 independent shfl per keep)
__global__ __launch_bounds__(64) void k_scan(const u64* __restrict__ mask,
                                             const double4* __restrict__ sboxes,
                                             float* __restrict__ out) {
  __shared__ int keepL[POST_NMS];
  int lane = threadIdx.x;
  for (int r = lane; r < POST_NMS; r += 64) keepL[r] = 0;

  int kreg0 = 0, kreg1 = 0, kreg2 = 0, kreg3 = 0, kreg4 = 0; // keep idx at q*64+lane
  int nkeep = 0;
  bool done = false;

  // current chunk's diagonal tile: cQwT = row (c*256 + Q*64 + lane), word 4c+T
  u64 c0w0, c0w1, c0w2, c0w3, c1w0, c1w1, c1w2, c1w3;
  u64 c2w0, c2w1, c2w2, c2w3, c3w0, c3w1, c3w2, c3w3;

  // tail guard: words 4c+2, 4c+3 exist iff 4c+2 < 94 (false only for c=23,
  // where 4c+3 = 95 is also out; 4c and 4c+1 are always < 94).
#define DIAG_LOAD(cc, Q, w0v, w1v, w2v, w3v)                                   \
  {                                                                            \
    int row_ = ((cc) << 8) + ((Q) << 6) + lane;                                \
    w0v = 0; w1v = 0; w2v = 0; w3v = 0;                                        \
    if (row_ < PRE_NMS) {                                                      \
      const u64* p_ = mask + (size_t)row_ * NWORDS + ((cc) << 2);              \
      w0v = p_[0];                                                             \
      w1v = p_[1];                                                             \
      if (((cc) << 2) + 2 < NWORDS) { w2v = p_[2]; w3v = p_[3]; }              \
    }                                                                          \
  }

  DIAG_LOAD(0, 0, c0w0, c0w1, c0w2, c0w3)
  DIAG_LOAD(0, 1, c1w0, c1w1, c1w2, c1w3)
  DIAG_LOAD(0, 2, c2w0, c2w1, c2w2, c2w3)
  DIAG_LOAD(0, 3, c3w0, c3w1, c3w2, c3w3)

  for (int c = 0; c < NCHUNK && !done; ++c) {
    int wbase = c << 2;
    bool tail_ok = (wbase + 2) < NWORDS;

    // prefetch next chunk's diagonal tile (issued early, consumed at loop end)
    u64 n0w0 = 0, n0w1 = 0, n0w2 = 0, n0w3 = 0;
    u64 n1w0 = 0, n1w1 = 0, n1w2 = 0, n1w3 = 0;
    u64 n2w0 = 0, n2w1 = 0, n2w2 = 0, n2w3 = 0;
    u64 n3w0 = 0, n3w1 = 0, n3w2 = 0, n3w3 = 0;
    if (c + 1 < NCHUNK) {
      DIAG_LOAD(c + 1, 0, n0w0, n0w1, n0w2, n0w3)
      DIAG_LOAD(c + 1, 1, n1w0, n1w1, n1w2, n1w3)
      DIAG_LOAD(c + 1, 2, n2w0, n2w1, n2w2, n2w3)
      DIAG_LOAD(c + 1, 3, n3w0, n3w1, n3w2, n3w3)
    }

    // gather OR of kept rows' words [4c, 4c+4) (independent loads, one wait)
    int nq = (nkeep + 63) >> 6;
    u64 g00 = 0, g01 = 0, g02 = 0, g03 = 0;
    u64 g10 = 0, g11 = 0, g12 = 0, g13 = 0;
    u64 g20 = 0, g21 = 0, g22 = 0, g23 = 0;
    u64 g30 = 0, g31 = 0, g32 = 0, g33 = 0;
    u64 g40 = 0, g41 = 0, g42 = 0, g43 = 0;
#define GATHER(KR, a0, a1, a2, a3)                                             \
    {                                                                          \
      const u64* p_ = mask + (size_t)(KR) * NWORDS + wbase;                    \
      a0 = p_[0];                                                              \
      a1 = p_[1];                                                              \
      if (tail_ok) { a2 = p_[2]; a3 = p_[3]; }                                 \
    }
    if (nq > 0) GATHER(kreg0, g00, g01, g02, g03)
    if (nq > 1) GATHER(kreg1, g10, g11, g12, g13)
    if (nq > 2) GATHER(kreg2, g20, g21, g22, g23)
    if (nq > 3) GATHER(kreg3, g30, g31, g32, g33)
    if (nq > 4) GATHER(kreg4, g40, g41, g42, g43)
#undef GATHER
    u64 or0 = 0, or1 = 0, or2 = 0, or3 = 0;
    if (lane < nkeep)       { or0 |= g00; or1 |= g01; or2 |= g02; or3 |= g03; }
    if (64 + lane < nkeep)  { or0 |= g10; or1 |= g11; or2 |= g12; or3 |= g13; }
    if (128 + lane < nkeep) { or0 |= g20; or1 |= g21; or2 |= g22; or3 |= g23; }
    if (192 + lane < nkeep) { or0 |= g30; or1 |= g31; or2 |= g32; or3 |= g33; }
    if (256 + lane < nkeep) { or0 |= g40; or1 |= g41; or2 |= g42; or3 |= g43; }
    #pragma unroll
    for (int m = 32; m; m >>= 1) {
      or0 |= __shfl_xor(or0, m);
      or1 |= __shfl_xor(or1, m);
      or2 |= __shfl_xor(or2, m);
      or3 |= __shfl_xor(or3, m);
    }

    u64 alive0 = ~or0 & valid_word(wbase);
    u64 alive1 = ~or1 & valid_word(wbase + 1);
    u64 alive2 = ~or2 & valid_word(wbase + 2);
    u64 alive3 = ~or3 & valid_word(wbase + 3);

    while (alive0 | alive1 | alive2 | alive3) {
      int word, b;
      if (alive0) { word = 0; b = __builtin_ctzll(alive0); }
      else if (alive1) { word = 1; b = __builtin_ctzll(alive1); }
      else if (alive2) { word = 2; b = __builtin_ctzll(alive2); }
      else { word = 3; b = __builtin_ctzll(alive3); }
      int K = (c << 8) + (word << 6) + b;
      if (lane == 0) keepL[nkeep] = K;
      int q = nkeep >> 6, l = nkeep & 63;
      if (lane == l) {
        if (q == 0) kreg0 = K;
        else if (q == 1) kreg1 = K;
        else if (q == 2) kreg2 = K;
        else if (q == 3) kreg3 = K;
        else kreg4 = K;
      }
      ++nkeep;
      if (nkeep >= POST_NMS) { done = true; break; }
      // broadcast row K's 4 words from lane b of quadrant `word`
      u64 s0 = (word == 0) ? c0w0 : (word == 1) ? c1w0 : (word == 2) ? c2w0 : c3w0;
      u64 s1 = (word == 0) ? c0w1 : (word == 1) ? c1w1 : (word == 2) ? c2w1 : c3w1;
      u64 s2 = (word == 0) ? c0w2 : (word == 1) ? c1w2 : (word == 2) ? c2w2 : c3w2;
      u64 s3 = (word == 0) ? c0w3 : (word == 1) ? c1w3 : (word == 2) ? c2w3 : c3w3;
      u64 r0 = __shfl(s0, b), r1 = __shfl(s1, b), r2 = __shfl(s2, b), r3 = __shfl(s3, b);
      if (word == 0) r0 |= (1ULL << b);
      else if (word == 1) r1 |= (1ULL << b);
      else if (word == 2) r2 |= (1ULL << b);
      else r3 |= (1ULL << b);
      alive0 &= ~r0; alive1 &= ~r1; alive2 &= ~r2; alive3 &= ~r3;
    }

    c0w0 = n0w0; c0w1 = n0w1; c0w2 = n0w2; c0w3 = n0w3;
    c1w0 = n1w0; c1w1 = n1w1; c1w2 = n1w2; c1w3 = n1w3;
    c2w0 = n2w0; c2w1 = n2w1; c2w2 = n2w2; c2w3 = n2w3;
    c3w0 = n3w0; c3w1 = n3w1; c3w2 = n3w2; c3w3 = n3w3;
  }
#undef DIAG_LOAD
  __syncthreads();

  for (int r = lane; r < POST_NMS; r += 64) {
    int kk = keepL[r];
    double4 b = sboxes[kk];
    float* o = out + r * 5;
    o[0] = 0.0f;
    o[1] = (float)b.x;
    o[2] = (float)b.y;
    o[3] = (float)b.z;
    o[4] = (float)b.w;
  }
}

extern "C" void kernel_launch(void* const* d_in, const int* in_sizes, int n_in,
                              void* d_out, int out_size, void* d_ws, size_t ws_size,
                              hipStream_t stream) {
  const float* cls = (const float*)d_in[0];
  const float* bbox = (const float*)d_in[1];
  const int* imh = (const int*)d_in[2];
  const int* imw = (const int*)d_in[3];
  float* out = (float*)d_out;

  // Workspace (identical footprint to the proven 227us baseline):
  // [0, 192512)         sboxes (6016 double4)
  // [192512, +4512000)  mask (6000*94 u64); A/B key/val buffers overlay the
  //                     front of mask (dead before k_mask runs).
  char* p = (char*)d_ws;
  double4* sboxes = (double4*)p;
  char* mb = p + 192512;
  u64* maskbuf = (u64*)mb;
  u64* Ak = (u64*)mb;                       // 65536 u64 (512 KB)
  u32* Av = (u32*)(mb + 524288);            // 65536 u32 (256 KB)
  u64* Bk = (u64*)(mb + 786432);            // 512 KB
  u32* Bv = (u32*)(mb + 1310720);           // 256 KB

  k_score_sort<<<64, 512, 0, stream>>>(cls, bbox, imh, imw, Ak, Av);
  k_merge1<<<NPAD / 256, 256, 0, stream>>>(Ak, Av, Bk, Bv);
  k_merge2<<<NPAD / 256, 256, 0, stream>>>(Bk, Bv, Ak, Av);
  k_merge3<<<(4 * CAP) / 256, 256, 0, stream>>>(Ak, Av, bbox, imh, imw, sboxes);
  k_mask<<<dim3(NWORDS, NWORDS), 64, 0, stream>>>(sboxes, maskbuf);
  k_scan<<<1, 64, 0, stream>>>(maskbuf, sboxes, out);
}

// Round 5
// 188.602 us; speedup vs baseline: 1.4482x; 1.4482x over previous
//
#include <hip/hip_runtime.h>

typedef unsigned long long u64;
typedef unsigned int u32;

#define FEAT_W 100
#define NANCH 9
#define NTOT 57600
#define NPAD 65536
#define PRE_NMS 6000
#define POST_NMS 300
#define NBLK 94        // 64-box blocks (mask words per full row)
#define NCHUNK 24      // 4 words (256 boxes) per k_scan iteration
#define CH_STRIDE 6400
#define CHUNK 1024
#define CAP 6144

__constant__ double c_base[9][4] = {
    {-84.0, -40.0, 99.0, 55.0},    {-176.0, -88.0, 191.0, 103.0},
    {-360.0, -184.0, 375.0, 199.0},{-56.0, -56.0, 71.0, 71.0},
    {-120.0, -120.0, 135.0, 135.0},{-248.0, -248.0, 263.0, 263.0},
    {-36.0, -80.0, 51.0, 95.0},    {-80.0, -168.0, 95.0, 183.0},
    {-168.0, -344.0, 183.0, 359.0}};

struct BoxD { double x1, y1, x2, y2; };

// Packed upper-triangular mask: row i stores words [i>>6, 94).
// off(i) = 94*i - 32*q*(q-1) - r*q, q=i>>6, r=i&63.  Total 285744 words (2.29MB).
__device__ __forceinline__ int packed_off(int i) {
  int q = i >> 6, r = i & 63;
  return 94 * i - 32 * q * (q - 1) - r * q;
}

__device__ __forceinline__ BoxD decode_box(int i, const float* __restrict__ bbox,
                                           double imw1, double imh1) {
  int pos = i / NANCH;
  int a = i - pos * NANCH;
  int h = pos / FEAT_W;
  int w = pos - h * FEAT_W;
  double ax1 = c_base[a][0] + 16.0 * (double)w;
  double ay1 = c_base[a][1] + 16.0 * (double)h;
  double ax2 = c_base[a][2] + 16.0 * (double)w;
  double ay2 = c_base[a][3] + 16.0 * (double)h;
  double wd = ax2 - ax1 + 1.0;
  double hg = ay2 - ay1 + 1.0;
  double cx = ax1 + 0.5 * wd;
  double cy = ay1 + 0.5 * hg;
  const float* bp = bbox + (size_t)(4 * a) * CH_STRIDE + pos;
  double dx = (double)bp[0];
  double dy = (double)bp[CH_STRIDE];
  double dw = (double)bp[2 * CH_STRIDE];
  double dh = (double)bp[3 * CH_STRIDE];
  double pcx = dx * wd + cx;
  double pcy = dy * hg + cy;
  double pw = exp(dw) * wd;
  double ph = exp(dh) * hg;
  BoxD b;
  b.x1 = fmin(fmax(pcx - 0.5 * pw, 0.0), imw1);
  b.y1 = fmin(fmax(pcy - 0.5 * ph, 0.0), imh1);
  b.x2 = fmin(fmax(pcx + 0.5 * pw, 0.0), imw1);
  b.y2 = fmin(fmax(pcy + 0.5 * ph, 0.0), imh1);
  return b;
}

__device__ __forceinline__ u64 score_key(int i, const float* __restrict__ cls,
                                         const float* __restrict__ bbox,
                                         double imw1, double imh1) {
  BoxD b = decode_box(i, bbox, imw1, imh1);
  bool valid = (b.x2 - b.x1 + 1.0 >= 16.0) && (b.y2 - b.y1 + 1.0 >= 16.0);
  int pos = i / NANCH;
  int a = i - pos * NANCH;
  double c0 = (double)cls[(size_t)(2 * a) * CH_STRIDE + pos];
  double c1 = (double)cls[(size_t)(2 * a + 1) * CH_STRIDE + pos];
  double m = fmax(c0, c1);
  double e0 = exp(c0 - m), e1 = exp(c1 - m);
  double s = e1 / (e0 + e1);
  double masked = valid ? s : (double)(-1e30f);
  u64 u = (u64)__double_as_longlong(masked);
  return (u >> 63) ? ~u : (u | 0x8000000000000000ULL);
}

__device__ __forceinline__ bool before(u64 ka, u32 va, u64 kb, u32 vb) {
  return (ka > kb) || (ka == kb && va < vb);
}
__device__ __forceinline__ bool comes_after(u64 ka, u32 va, u64 kb, u32 vb) {
  return (ka < kb) || (ka == kb && va > vb);
}

__device__ __forceinline__ int count_before(const u64* Sk, const u32* Sv, int n,
                                            u64 k, u32 v) {
  int lo = 0, hi = n;
  while (lo < hi) {
    int m = (lo + hi) >> 1;
    if (before(Sk[m], Sv[m], k, v)) lo = m + 1; else hi = m;
  }
  return lo;
}

// 64 blocks: compute 1024 keys, bitonic-sort in LDS (55 stages), write chunk.
__global__ __launch_bounds__(512) void k_score_sort(
    const float* __restrict__ cls, const float* __restrict__ bbox,
    const int* __restrict__ imh, const int* __restrict__ imw,
    u64* __restrict__ keys, u32* __restrict__ vals) {
  __shared__ u64 sk[CHUNK];
  __shared__ u32 sv[CHUNK];
  int base = blockIdx.x * CHUNK;
  double imh1 = (double)(imh[0] - 1);
  double imw1 = (double)(imw[0] - 1);
  for (int t = threadIdx.x; t < CHUNK; t += 512) {
    int i = base + t;
    if (i < NTOT) { sk[t] = score_key(i, cls, bbox, imw1, imh1); sv[t] = (u32)i; }
    else { sk[t] = 0ULL; sv[t] = (u32)i; }
  }
  __syncthreads();
  for (int k = 2; k <= CHUNK; k <<= 1) {
    for (int j = k >> 1; j > 0; j >>= 1) {
      int t = threadIdx.x;
      int i = ((t & ~(j - 1)) << 1) | (t & (j - 1));
      int l = i | j;
      bool up = ((i & k) == 0);
      u64 ka = sk[i], kb = sk[l];
      u32 va = sv[i], vb = sv[l];
      if (comes_after(ka, va, kb, vb) == up) { sk[i] = kb; sv[i] = vb; sk[l] = ka; sv[l] = va; }
      __syncthreads();
    }
  }
  for (int t = threadIdx.x; t < CHUNK; t += 512) { keys[base + t] = sk[t]; vals[base + t] = sv[t]; }
}

// r1: 64 lists x1024 -> 16 x4096 (A -> B), 4-way rank-merge.
__global__ void k_merge1(const u64* __restrict__ Ak, const u32* __restrict__ Av,
                         u64* __restrict__ Bk, u32* __restrict__ Bv) {
  int gtid = blockIdx.x * blockDim.x + threadIdx.x;
  if (gtid >= NPAD) return;
  int lst = gtid >> 10, pos = gtid & 1023, grp = lst >> 2;
  u64 k = Ak[gtid]; u32 v = Av[gtid];
  int rank = pos;
  int b0 = grp << 2;
  #pragma unroll
  for (int s = 0; s < 4; ++s)
    if ((b0 + s) != lst)
      rank += count_before(Ak + (size_t)(b0 + s) * 1024, Av + (size_t)(b0 + s) * 1024, 1024, k, v);
  Bk[(size_t)grp * 4096 + rank] = k;
  Bv[(size_t)grp * 4096 + rank] = v;
}

// r2: 16 lists x4096 -> 4 x6144 (B -> A), truncated.
__global__ void k_merge2(const u64* __restrict__ Bk, const u32* __restrict__ Bv,
                         u64* __restrict__ Ak, u32* __restrict__ Av) {
  int gtid = blockIdx.x * blockDim.x + threadIdx.x;
  if (gtid >= NPAD) return;
  int lst = gtid >> 12, pos = gtid & 4095, grp = lst >> 2;
  u64 k = Bk[gtid]; u32 v = Bv[gtid];
  int rank = pos;
  int b0 = grp << 2;
  #pragma unroll
  for (int s = 0; s < 4; ++s)
    if ((b0 + s) != lst)
      rank += count_before(Bk + (size_t)(b0 + s) * 4096, Bv + (size_t)(b0 + s) * 4096, 4096, k, v);
  if (rank < CAP) { Ak[(size_t)grp * CAP + rank] = k; Av[(size_t)grp * CAP + rank] = v; }
}

// r3: 4 lists x6144 -> top-6000, fused with box decode into sboxes.
__global__ void k_merge3(const u64* __restrict__ Ak, const u32* __restrict__ Av,
                         const float* __restrict__ bbox, const int* __restrict__ imh,
                         const int* __restrict__ imw, double4* __restrict__ sboxes) {
  int gtid = blockIdx.x * blockDim.x + threadIdx.x;
  if (gtid >= 4 * CAP) return;
  int lst = gtid / CAP, pos = gtid - lst * CAP;
  u64 k = Ak[gtid]; u32 v = Av[gtid];
  int rank = pos;
  #pragma unroll
  for (int s = 0; s < 4; ++s)
    if (s != lst)
      rank += count_before(Ak + (size_t)s * CAP, Av + (size_t)s * CAP, CAP, k, v);
  if (rank < PRE_NMS) {
    double imh1 = (double)(imh[0] - 1);
    double imw1 = (double)(imw[0] - 1);
    BoxD b = decode_box((int)v, bbox, imw1, imh1);
    sboxes[rank] = make_double4(b.x1, b.y1, b.x2, b.y2);
  }
}

// IoU mask, packed upper-tri rows + per-chunk column tiles (colC).
// colC[J][t'] (t'=0..3) = bits over rows i (block 4*(J>>8)+t') of
// over(i,J) & (i < J).
__global__ void k_mask(const double4* __restrict__ sboxes, u64* __restrict__ mask,
                       u64* __restrict__ colC) {
  __shared__ double4 cb[64];
  int bc = blockIdx.x, br = blockIdx.y;
  int t = threadIdx.x;
  bool samechunk = (bc >> 2) == (br >> 2);
  if (bc < br) {
    // strictly lower-triangular block: no packed storage; zero colC slot.
    if (samechunk) colC[(size_t)(((bc << 6) + t) * 4 + (br & 3))] = 0;
    return;
  }
  int j0 = bc * 64;
  int jt = j0 + t;
  cb[t] = (jt < PRE_NMS) ? sboxes[jt] : make_double4(0.0, 0.0, 0.0, 0.0);
  __syncthreads();
  int i = br * 64 + t;
  u64 bits = 0;
  if (i < PRE_NMS) {
    double4 rb = sboxes[i];
    double areai = (rb.z - rb.x) * (rb.w - rb.y);
    int cmax = min(64, PRE_NMS - j0);
    for (int c = 0; c < cmax; ++c) {
      int j = j0 + c;
      if (j <= i) continue;
      double4 cbx = cb[c];
      double xx1 = fmax(rb.x, cbx.x), yy1 = fmax(rb.y, cbx.y);
      double xx2 = fmin(rb.z, cbx.z), yy2 = fmin(rb.w, cbx.w);
      double w = fmax(xx2 - xx1, 0.0), h = fmax(yy2 - yy1, 0.0);
      double inter = w * h;
      double areaj = (cbx.z - cbx.x) * (cbx.w - cbx.y);
      double iou = inter / (areai + areaj - inter);
      if (iou > 0.7) bits |= (1ULL << c);
    }
    mask[(size_t)(packed_off(i) + (bc - br))] = bits;
  }
  // ballot-transpose this 64x64 tile into column-major colC (in-chunk only).
  // All 64 lanes participate (rows >= PRE_NMS contribute bits = 0).
  if (samechunk) {
    u64 colbits = 0;
    for (int j2 = 0; j2 < 64; ++j2) {
      u64 bl = __ballot(((bits >> j2) & 1ULL) != 0);
      if (t == j2) colbits = bl;
    }
    colC[(size_t)(((bc << 6) + t) * 4 + (br & 3))] = colbits;
  }
}

__device__ __forceinline__ u64 valid_word(int w) {
  int base = w << 6;
  if (base >= PRE_NMS) return 0ULL;
  if (base + 64 <= PRE_NMS) return ~0ULL;
  return (1ULL << (PRE_NMS - base)) - 1ULL;
}

// Greedy NMS scan, single wave. v4: 256-box chunks (24 dependent-latency
// iterations) with BALLOT-based suppression — no per-keep shfl/select tree.
//  - gather: kept rows' packed words [4c,4c+4); every keep is from a chunk
//    before c, so its word index K>>6 < 4c and the packed read is always
//    within the row's stored range. Addresses precomputed into keepA LDS.
//  - intra-chunk: lane j holds colC[c*256 + T*64 + j][0..3]. Per keep b in
//    word T: alive &= ~(ballot((ct_TT >> b) & 1) | 1 << b). Cross-word
//    within chunk: one ballot of (col & kf[t']) per earlier word.
__global__ __launch_bounds__(64) void k_scan(const u64* __restrict__ mask,
                                             const u64* __restrict__ colC,
                                             const double4* __restrict__ sboxes,
                                             float* __restrict__ out) {
  __shared__ int keepIdx[320];
  __shared__ int keepA[320];   // packed word-base addr for gathers
  int lane = threadIdx.x;
  for (int r = lane; r < 320; r += 64) { keepIdx[r] = 0; keepA[r] = 0; }
  int nkeep = 0;
  bool done = false;

  // column tiles for current chunk: ct{T}{tp} = colC[c*256+T*64+lane][tp]
  u64 ct00, ct01, ct02, ct03, ct10, ct11, ct12, ct13;
  u64 ct20, ct21, ct22, ct23, ct30, ct31, ct32, ct33;

#define COL_LOAD(cc, T, a0, a1, a2, a3)                                        \
  {                                                                            \
    int J_ = ((cc) << 8) + ((T) << 6) + lane;                                  \
    a0 = 0; a1 = 0; a2 = 0; a3 = 0;                                            \
    if (J_ < PRE_NMS) {                                                        \
      const ulonglong2* p_ = (const ulonglong2*)(colC + (size_t)J_ * 4);       \
      ulonglong2 x_ = p_[0], y_ = p_[1];                                       \
      a0 = x_.x; a1 = x_.y; a2 = y_.x; a3 = y_.y;                              \
    }                                                                          \
  }

  COL_LOAD(0, 0, ct00, ct01, ct02, ct03)
  COL_LOAD(0, 1, ct10, ct11, ct12, ct13)
  COL_LOAD(0, 2, ct20, ct21, ct22, ct23)
  COL_LOAD(0, 3, ct30, ct31, ct32, ct33)

  for (int c = 0; c < NCHUNK && !done; ++c) {
    int wbase = c << 2;
    bool tail_ok = (wbase + 2) < NBLK;  // false only for c=23 (words 94,95 absent)

    // prefetch next chunk's column tiles (consumed at loop end)
    u64 n00 = 0, n01 = 0, n02 = 0, n03 = 0, n10 = 0, n11 = 0, n12 = 0, n13 = 0;
    u64 n20 = 0, n21 = 0, n22 = 0, n23 = 0, n30 = 0, n31 = 0, n32 = 0, n33 = 0;
    if (c + 1 < NCHUNK) {
      COL_LOAD(c + 1, 0, n00, n01, n02, n03)
      COL_LOAD(c + 1, 1, n10, n11, n12, n13)
      COL_LOAD(c + 1, 2, n20, n21, n22, n23)
      COL_LOAD(c + 1, 3, n30, n31, n32, n33)
    }

    // gather OR of kept rows' packed words [4c,4c+4)
    int nq = (nkeep + 63) >> 6;
    int a0 = keepA[lane], a1 = keepA[64 + lane], a2 = keepA[128 + lane];
    int a3 = keepA[192 + lane], a4 = keepA[256 + lane];
    u64 g00 = 0, g01 = 0, g02 = 0, g03 = 0;
    u64 g10 = 0, g11 = 0, g12 = 0, g13 = 0;
    u64 g20 = 0, g21 = 0, g22 = 0, g23 = 0;
    u64 g30 = 0, g31 = 0, g32 = 0, g33 = 0;
    u64 g40 = 0, g41 = 0, g42 = 0, g43 = 0;
#define GATHER(AA, x0, x1, x2, x3)                                             \
    {                                                                          \
      const u64* p_ = mask + (size_t)(AA) + wbase;                             \
      x0 = p_[0];                                                              \
      x1 = p_[1];                                                              \
      if (tail_ok) { x2 = p_[2]; x3 = p_[3]; }                                 \
    }
    if (nq > 0) GATHER(a0, g00, g01, g02, g03)
    if (nq > 1) GATHER(a1, g10, g11, g12, g13)
    if (nq > 2) GATHER(a2, g20, g21, g22, g23)
    if (nq > 3) GATHER(a3, g30, g31, g32, g33)
    if (nq > 4) GATHER(a4, g40, g41, g42, g43)
#undef GATHER
    u64 or0 = 0, or1 = 0, or2 = 0, or3 = 0;
    if (lane < nkeep)       { or0 |= g00; or1 |= g01; or2 |= g02; or3 |= g03; }
    if (64 + lane < nkeep)  { or0 |= g10; or1 |= g11; or2 |= g12; or3 |= g13; }
    if (128 + lane < nkeep) { or0 |= g20; or1 |= g21; or2 |= g22; or3 |= g23; }
    if (192 + lane < nkeep) { or0 |= g30; or1 |= g31; or2 |= g32; or3 |= g33; }
    if (256 + lane < nkeep) { or0 |= g40; or1 |= g41; or2 |= g42; or3 |= g43; }
    #pragma unroll
    for (int m = 32; m; m >>= 1) {
      or0 |= __shfl_xor(or0, m);
      or1 |= __shfl_xor(or1, m);
      or2 |= __shfl_xor(or2, m);
      or3 |= __shfl_xor(or3, m);
    }

    u64 kf0 = 0, kf1 = 0, kf2 = 0, kf3 = 0;

#define RUN_WORD(OR_, TT, DIAGC, CROSS_EXPR, KFVAR)                            \
    if (!done) {                                                               \
      u64 alive = ~(OR_) & valid_word(wbase + (TT));                           \
      u64 cross_ = (CROSS_EXPR);                                               \
      alive &= ~__ballot(cross_ != 0);                                         \
      u64 kfacc = 0;                                                           \
      while (alive) {                                                          \
        int b = __builtin_ctzll(alive);                                        \
        int K = (c << 8) + ((TT) << 6) + b;                                    \
        if (lane == 0) {                                                       \
          keepIdx[nkeep] = K;                                                  \
          keepA[nkeep] = packed_off(K) - (K >> 6);                             \
        }                                                                      \
        kfacc |= (1ULL << b);                                                  \
        ++nkeep;                                                               \
        if (nkeep >= POST_NMS) { done = true; break; }                         \
        u64 sup_ = __ballot((((DIAGC) >> b) & 1ULL) != 0);                     \
        alive &= ~(sup_ | (1ULL << b));                                        \
      }                                                                        \
      KFVAR = kfacc;                                                           \
    }

    RUN_WORD(or0, 0, ct00, 0ULL, kf0)
    RUN_WORD(or1, 1, ct11, (ct10 & kf0), kf1)
    RUN_WORD(or2, 2, ct22, (ct20 & kf0) | (ct21 & kf1), kf2)
    RUN_WORD(or3, 3, ct33, (ct30 & kf0) | (ct31 & kf1) | (ct32 & kf2), kf3)
#undef RUN_WORD
    (void)kf3;

    ct00 = n00; ct01 = n01; ct02 = n02; ct03 = n03;
    ct10 = n10; ct11 = n11; ct12 = n12; ct13 = n13;
    ct20 = n20; ct21 = n21; ct22 = n22; ct23 = n23;
    ct30 = n30; ct31 = n31; ct32 = n32; ct33 = n33;
  }
#undef COL_LOAD
  __syncthreads();

  for (int r = lane; r < POST_NMS; r += 64) {
    int kk = keepIdx[r];
    double4 b = sboxes[kk];
    float* o = out + r * 5;
    o[0] = 0.0f;
    o[1] = (float)b.x;
    o[2] = (float)b.y;
    o[3] = (float)b.z;
    o[4] = (float)b.w;
  }
}

extern "C" void kernel_launch(void* const* d_in, const int* in_sizes, int n_in,
                              void* d_out, int out_size, void* d_ws, size_t ws_size,
                              hipStream_t stream) {
  const float* cls = (const float*)d_in[0];
  const float* bbox = (const float*)d_in[1];
  const int* imh = (const int*)d_in[2];
  const int* imw = (const int*)d_in[3];
  float* out = (float*)d_out;

  // Workspace (2.67 MB total — SHRUNK vs the proven 4.70 MB footprint):
  // [0, 192512)          sboxes (6016 double4)
  // [192512, 385024)     colC   (6016 x 4 u64 column tiles)
  // [385024, 2670976)    packed upper-tri mask (285744 u64)
  //                      A/B key/val buffers (1.57MB) overlay the front of
  //                      the mask region (dead before k_mask runs).
  char* p = (char*)d_ws;
  double4* sboxes = (double4*)p;
  u64* colC = (u64*)(p + 192512);
  char* mb = p + 385024;
  u64* maskbuf = (u64*)mb;
  u64* Ak = (u64*)mb;                       // 65536 u64 (512 KB)
  u32* Av = (u32*)(mb + 524288);            // 65536 u32 (256 KB)
  u64* Bk = (u64*)(mb + 786432);            // 512 KB
  u32* Bv = (u32*)(mb + 1310720);           // 256 KB

  k_score_sort<<<64, 512, 0, stream>>>(cls, bbox, imh, imw, Ak, Av);
  k_merge1<<<NPAD / 256, 256, 0, stream>>>(Ak, Av, Bk, Bv);
  k_merge2<<<NPAD / 256, 256, 0, stream>>>(Bk, Bv, Ak, Av);
  k_merge3<<<(4 * CAP) / 256, 256, 0, stream>>>(Ak, Av, bbox, imh, imw, sboxes);
  k_mask<<<dim3(NBLK, NBLK), 64, 0, stream>>>(sboxes, maskbuf, colC);
  k_scan<<<1, 64, 0, stream>>>(maskbuf, colC, sboxes, out);
}

// Round 6
// 152.901 us; speedup vs baseline: 1.7864x; 1.2335x over previous
//
#include <hip/hip_runtime.h>

typedef unsigned long long u64;
typedef unsigned int u32;

#define FEAT_W 100
#define NANCH 9
#define NTOT 57600
#define NPAD 65536
#define PRE_NMS 6000
#define POST_NMS 300
#define NBLK 94        // 64-box blocks (mask words per full row)
#define NCHUNK 24      // 4 words (256 boxes) per k_scan iteration
#define CH_STRIDE 6400
#define CHUNK 1024
#define CAP 6144

__constant__ double c_base[9][4] = {
    {-84.0, -40.0, 99.0, 55.0},    {-176.0, -88.0, 191.0, 103.0},
    {-360.0, -184.0, 375.0, 199.0},{-56.0, -56.0, 71.0, 71.0},
    {-120.0, -120.0, 135.0, 135.0},{-248.0, -248.0, 263.0, 263.0},
    {-36.0, -80.0, 51.0, 95.0},    {-80.0, -168.0, 95.0, 183.0},
    {-168.0, -344.0, 183.0, 359.0}};

struct BoxD { double x1, y1, x2, y2; };

// Packed upper-triangular mask: row i stores words [i>>6, 94).
// off(i) = 94*i - 32*q*(q-1) - r*q, q=i>>6, r=i&63.  Total 285744 words (2.29MB).
__device__ __forceinline__ int packed_off(int i) {
  int q = i >> 6, r = i & 63;
  return 94 * i - 32 * q * (q - 1) - r * q;
}

__device__ __forceinline__ BoxD decode_box(int i, const float* __restrict__ bbox,
                                           double imw1, double imh1) {
  int pos = i / NANCH;
  int a = i - pos * NANCH;
  int h = pos / FEAT_W;
  int w = pos - h * FEAT_W;
  double ax1 = c_base[a][0] + 16.0 * (double)w;
  double ay1 = c_base[a][1] + 16.0 * (double)h;
  double ax2 = c_base[a][2] + 16.0 * (double)w;
  double ay2 = c_base[a][3] + 16.0 * (double)h;
  double wd = ax2 - ax1 + 1.0;
  double hg = ay2 - ay1 + 1.0;
  double cx = ax1 + 0.5 * wd;
  double cy = ay1 + 0.5 * hg;
  const float* bp = bbox + (size_t)(4 * a) * CH_STRIDE + pos;
  double dx = (double)bp[0];
  double dy = (double)bp[CH_STRIDE];
  double dw = (double)bp[2 * CH_STRIDE];
  double dh = (double)bp[3 * CH_STRIDE];
  double pcx = dx * wd + cx;
  double pcy = dy * hg + cy;
  double pw = exp(dw) * wd;
  double ph = exp(dh) * hg;
  BoxD b;
  b.x1 = fmin(fmax(pcx - 0.5 * pw, 0.0), imw1);
  b.y1 = fmin(fmax(pcy - 0.5 * ph, 0.0), imh1);
  b.x2 = fmin(fmax(pcx + 0.5 * pw, 0.0), imw1);
  b.y2 = fmin(fmax(pcy + 0.5 * ph, 0.0), imh1);
  return b;
}

__device__ __forceinline__ u64 score_key(int i, const float* __restrict__ cls,
                                         const float* __restrict__ bbox,
                                         double imw1, double imh1) {
  BoxD b = decode_box(i, bbox, imw1, imh1);
  bool valid = (b.x2 - b.x1 + 1.0 >= 16.0) && (b.y2 - b.y1 + 1.0 >= 16.0);
  int pos = i / NANCH;
  int a = i - pos * NANCH;
  double c0 = (double)cls[(size_t)(2 * a) * CH_STRIDE + pos];
  double c1 = (double)cls[(size_t)(2 * a + 1) * CH_STRIDE + pos];
  double m = fmax(c0, c1);
  double e0 = exp(c0 - m), e1 = exp(c1 - m);
  double s = e1 / (e0 + e1);
  double masked = valid ? s : (double)(-1e30f);
  u64 u = (u64)__double_as_longlong(masked);
  return (u >> 63) ? ~u : (u | 0x8000000000000000ULL);
}

__device__ __forceinline__ bool before(u64 ka, u32 va, u64 kb, u32 vb) {
  return (ka > kb) || (ka == kb && va < vb);
}
__device__ __forceinline__ bool comes_after(u64 ka, u32 va, u64 kb, u32 vb) {
  return (ka < kb) || (ka == kb && va > vb);
}

__device__ __forceinline__ int count_before(const u64* Sk, const u32* Sv, int n,
                                            u64 k, u32 v) {
  int lo = 0, hi = n;
  while (lo < hi) {
    int m = (lo + hi) >> 1;
    if (before(Sk[m], Sv[m], k, v)) lo = m + 1; else hi = m;
  }
  return lo;
}

// 64 blocks: compute 1024 keys, bitonic-sort in LDS (55 stages), write chunk.
__global__ __launch_bounds__(512) void k_score_sort(
    const float* __restrict__ cls, const float* __restrict__ bbox,
    const int* __restrict__ imh, const int* __restrict__ imw,
    u64* __restrict__ keys, u32* __restrict__ vals) {
  __shared__ u64 sk[CHUNK];
  __shared__ u32 sv[CHUNK];
  int base = blockIdx.x * CHUNK;
  double imh1 = (double)(imh[0] - 1);
  double imw1 = (double)(imw[0] - 1);
  for (int t = threadIdx.x; t < CHUNK; t += 512) {
    int i = base + t;
    if (i < NTOT) { sk[t] = score_key(i, cls, bbox, imw1, imh1); sv[t] = (u32)i; }
    else { sk[t] = 0ULL; sv[t] = (u32)i; }
  }
  __syncthreads();
  for (int k = 2; k <= CHUNK; k <<= 1) {
    for (int j = k >> 1; j > 0; j >>= 1) {
      int t = threadIdx.x;
      int i = ((t & ~(j - 1)) << 1) | (t & (j - 1));
      int l = i | j;
      bool up = ((i & k) == 0);
      u64 ka = sk[i], kb = sk[l];
      u32 va = sv[i], vb = sv[l];
      if (comes_after(ka, va, kb, vb) == up) { sk[i] = kb; sv[i] = vb; sk[l] = ka; sv[l] = va; }
      __syncthreads();
    }
  }
  for (int t = threadIdx.x; t < CHUNK; t += 512) { keys[base + t] = sk[t]; vals[base + t] = sv[t]; }
}

// r1: 64 lists x1024 -> 16 x4096 (A -> B), 4-way rank-merge.
__global__ void k_merge1(const u64* __restrict__ Ak, const u32* __restrict__ Av,
                         u64* __restrict__ Bk, u32* __restrict__ Bv) {
  int gtid = blockIdx.x * blockDim.x + threadIdx.x;
  if (gtid >= NPAD) return;
  int lst = gtid >> 10, pos = gtid & 1023, grp = lst >> 2;
  u64 k = Ak[gtid]; u32 v = Av[gtid];
  int rank = pos;
  int b0 = grp << 2;
  #pragma unroll
  for (int s = 0; s < 4; ++s)
    if ((b0 + s) != lst)
      rank += count_before(Ak + (size_t)(b0 + s) * 1024, Av + (size_t)(b0 + s) * 1024, 1024, k, v);
  Bk[(size_t)grp * 4096 + rank] = k;
  Bv[(size_t)grp * 4096 + rank] = v;
}

// r2: 16 lists x4096 -> 4 x6144 (B -> A), truncated.
__global__ void k_merge2(const u64* __restrict__ Bk, const u32* __restrict__ Bv,
                         u64* __restrict__ Ak, u32* __restrict__ Av) {
  int gtid = blockIdx.x * blockDim.x + threadIdx.x;
  if (gtid >= NPAD) return;
  int lst = gtid >> 12, pos = gtid & 4095, grp = lst >> 2;
  u64 k = Bk[gtid]; u32 v = Bv[gtid];
  int rank = pos;
  int b0 = grp << 2;
  #pragma unroll
  for (int s = 0; s < 4; ++s)
    if ((b0 + s) != lst)
      rank += count_before(Bk + (size_t)(b0 + s) * 4096, Bv + (size_t)(b0 + s) * 4096, 4096, k, v);
  if (rank < CAP) { Ak[(size_t)grp * CAP + rank] = k; Av[(size_t)grp * CAP + rank] = v; }
}

// r3: 4 lists x6144 -> top-6000, fused with box decode into sboxes.
__global__ void k_merge3(const u64* __restrict__ Ak, const u32* __restrict__ Av,
                         const float* __restrict__ bbox, const int* __restrict__ imh,
                         const int* __restrict__ imw, double4* __restrict__ sboxes) {
  int gtid = blockIdx.x * blockDim.x + threadIdx.x;
  if (gtid >= 4 * CAP) return;
  int lst = gtid / CAP, pos = gtid - lst * CAP;
  u64 k = Ak[gtid]; u32 v = Av[gtid];
  int rank = pos;
  #pragma unroll
  for (int s = 0; s < 4; ++s)
    if (s != lst)
      rank += count_before(Ak + (size_t)s * CAP, Av + (size_t)s * CAP, CAP, k, v);
  if (rank < PRE_NMS) {
    double imh1 = (double)(imh[0] - 1);
    double imw1 = (double)(imw[0] - 1);
    BoxD b = decode_box((int)v, bbox, imw1, imh1);
    sboxes[rank] = make_double4(b.x1, b.y1, b.x2, b.y2);
  }
}

// IoU mask, packed upper-tri rows + per-chunk column tiles (colC).
// v5: division-free IoU decision (inter > 0.7*union <=> iou > 0.7; both in
// double, decision flips only within ~1e-16 of the boundary — far inside the
// >1e-7 margin the passing double-div version already implied).
__global__ void k_mask(const double4* __restrict__ sboxes, u64* __restrict__ mask,
                       u64* __restrict__ colC) {
  __shared__ double4 cb[64];
  int bc = blockIdx.x, br = blockIdx.y;
  int t = threadIdx.x;
  bool samechunk = (bc >> 2) == (br >> 2);
  if (bc < br) {
    // strictly lower-triangular block: no packed storage; zero colC slot.
    if (samechunk) colC[(size_t)(((bc << 6) + t) * 4 + (br & 3))] = 0;
    return;
  }
  int j0 = bc * 64;
  int jt = j0 + t;
  cb[t] = (jt < PRE_NMS) ? sboxes[jt] : make_double4(0.0, 0.0, 0.0, 0.0);
  __syncthreads();
  int i = br * 64 + t;
  u64 bits = 0;
  if (i < PRE_NMS) {
    double4 rb = sboxes[i];
    double areai = (rb.z - rb.x) * (rb.w - rb.y);
    int cmax = min(64, PRE_NMS - j0);
    for (int c = 0; c < cmax; ++c) {
      int j = j0 + c;
      if (j <= i) continue;
      double4 cbx = cb[c];
      double xx1 = fmax(rb.x, cbx.x), yy1 = fmax(rb.y, cbx.y);
      double xx2 = fmin(rb.z, cbx.z), yy2 = fmin(rb.w, cbx.w);
      double w = fmax(xx2 - xx1, 0.0), h = fmax(yy2 - yy1, 0.0);
      double inter = w * h;
      double areaj = (cbx.z - cbx.x) * (cbx.w - cbx.y);
      if (inter > 0.7 * (areai + areaj - inter)) bits |= (1ULL << c);
    }
    mask[(size_t)(packed_off(i) + (bc - br))] = bits;
  }
  // ballot-transpose this 64x64 tile into column-major colC (in-chunk only).
  // All 64 lanes participate (rows >= PRE_NMS contribute bits = 0).
  if (samechunk) {
    u64 colbits = 0;
    for (int j2 = 0; j2 < 64; ++j2) {
      u64 bl = __ballot(((bits >> j2) & 1ULL) != 0);
      if (t == j2) colbits = bl;
    }
    colC[(size_t)(((bc << 6) + t) * 4 + (br & 3))] = colbits;
  }
}

__device__ __forceinline__ u64 valid_word(int w) {
  int base = w << 6;
  if (base >= PRE_NMS) return 0ULL;
  if (base + 64 <= PRE_NMS) return ~0ULL;
  return (1ULL << (PRE_NMS - base)) - 1ULL;
}

// Greedy NMS scan, single wave. v5: same 24-chunk / ballot-suppression
// structure as v4, but keep bookkeeping is DEFERRED out of the serial inner
// loop: the while-loop only does {ctz, kfacc|=, ballot, alive&=~}; after the
// word completes, all 64 lanes write keepIdx/keepA in parallel (lane l
// handles bit l of kfacc, slot = nkeep + popc(kfacc below l)), and nkeep/done
// update once per word. Overshoot past POST_NMS inside one word is harmless:
// arrays sized 384 (max 299+64), output reads only [0,300).
__global__ __launch_bounds__(64) void k_scan(const u64* __restrict__ mask,
                                             const u64* __restrict__ colC,
                                             const double4* __restrict__ sboxes,
                                             float* __restrict__ out) {
  __shared__ int keepIdx[384];
  __shared__ int keepA[384];   // packed word-base addr for gathers
  int lane = threadIdx.x;
  for (int r = lane; r < 384; r += 64) { keepIdx[r] = 0; keepA[r] = 0; }
  int nkeep = 0;
  bool done = false;

  // column tiles for current chunk: ct{T}{tp} = colC[c*256+T*64+lane][tp]
  u64 ct00, ct01, ct02, ct03, ct10, ct11, ct12, ct13;
  u64 ct20, ct21, ct22, ct23, ct30, ct31, ct32, ct33;

#define COL_LOAD(cc, T, a0, a1, a2, a3)                                        \
  {                                                                            \
    int J_ = ((cc) << 8) + ((T) << 6) + lane;                                  \
    a0 = 0; a1 = 0; a2 = 0; a3 = 0;                                            \
    if (J_ < PRE_NMS) {                                                        \
      const ulonglong2* p_ = (const ulonglong2*)(colC + (size_t)J_ * 4);       \
      ulonglong2 x_ = p_[0], y_ = p_[1];                                       \
      a0 = x_.x; a1 = x_.y; a2 = y_.x; a3 = y_.y;                              \
    }                                                                          \
  }

  COL_LOAD(0, 0, ct00, ct01, ct02, ct03)
  COL_LOAD(0, 1, ct10, ct11, ct12, ct13)
  COL_LOAD(0, 2, ct20, ct21, ct22, ct23)
  COL_LOAD(0, 3, ct30, ct31, ct32, ct33)

  for (int c = 0; c < NCHUNK && !done; ++c) {
    int wbase = c << 2;
    bool tail_ok = (wbase + 2) < NBLK;  // false only for c=23 (words 94,95 absent)

    // prefetch next chunk's column tiles (consumed at loop end)
    u64 n00 = 0, n01 = 0, n02 = 0, n03 = 0, n10 = 0, n11 = 0, n12 = 0, n13 = 0;
    u64 n20 = 0, n21 = 0, n22 = 0, n23 = 0, n30 = 0, n31 = 0, n32 = 0, n33 = 0;
    if (c + 1 < NCHUNK) {
      COL_LOAD(c + 1, 0, n00, n01, n02, n03)
      COL_LOAD(c + 1, 1, n10, n11, n12, n13)
      COL_LOAD(c + 1, 2, n20, n21, n22, n23)
      COL_LOAD(c + 1, 3, n30, n31, n32, n33)
    }

    // gather OR of kept rows' packed words [4c,4c+4)
    int nq = (nkeep + 63) >> 6;
    int a0 = keepA[lane], a1 = keepA[64 + lane], a2 = keepA[128 + lane];
    int a3 = keepA[192 + lane], a4 = keepA[256 + lane];
    u64 g00 = 0, g01 = 0, g02 = 0, g03 = 0;
    u64 g10 = 0, g11 = 0, g12 = 0, g13 = 0;
    u64 g20 = 0, g21 = 0, g22 = 0, g23 = 0;
    u64 g30 = 0, g31 = 0, g32 = 0, g33 = 0;
    u64 g40 = 0, g41 = 0, g42 = 0, g43 = 0;
#define GATHER(AA, x0, x1, x2, x3)                                             \
    {                                                                          \
      const u64* p_ = mask + (size_t)(AA) + wbase;                             \
      x0 = p_[0];                                                              \
      x1 = p_[1];                                                              \
      if (tail_ok) { x2 = p_[2]; x3 = p_[3]; }                                 \
    }
    if (nq > 0) GATHER(a0, g00, g01, g02, g03)
    if (nq > 1) GATHER(a1, g10, g11, g12, g13)
    if (nq > 2) GATHER(a2, g20, g21, g22, g23)
    if (nq > 3) GATHER(a3, g30, g31, g32, g33)
    if (nq > 4) GATHER(a4, g40, g41, g42, g43)
#undef GATHER
    u64 or0 = 0, or1 = 0, or2 = 0, or3 = 0;
    if (lane < nkeep)       { or0 |= g00; or1 |= g01; or2 |= g02; or3 |= g03; }
    if (64 + lane < nkeep)  { or0 |= g10; or1 |= g11; or2 |= g12; or3 |= g13; }
    if (128 + lane < nkeep) { or0 |= g20; or1 |= g21; or2 |= g22; or3 |= g23; }
    if (192 + lane < nkeep) { or0 |= g30; or1 |= g31; or2 |= g32; or3 |= g33; }
    if (256 + lane < nkeep) { or0 |= g40; or1 |= g41; or2 |= g42; or3 |= g43; }
    #pragma unroll
    for (int m = 32; m; m >>= 1) {
      or0 |= __shfl_xor(or0, m);
      or1 |= __shfl_xor(or1, m);
      or2 |= __shfl_xor(or2, m);
      or3 |= __shfl_xor(or3, m);
    }

    u64 kf0 = 0, kf1 = 0, kf2 = 0, kf3 = 0;

#define RUN_WORD(OR_, TT, DIAGC, CROSS_EXPR, KFVAR)                            \
    if (!done) {                                                               \
      u64 alive = ~(OR_) & valid_word(wbase + (TT));                           \
      alive &= ~__ballot((CROSS_EXPR) != 0ULL);                                \
      u64 kfacc = 0;                                                           \
      while (alive) {                                                          \
        int b = __builtin_ctzll(alive);                                        \
        u64 bb = 1ULL << b;                                                    \
        kfacc |= bb;                                                           \
        u64 sup_ = __ballot((((DIAGC) >> b) & 1ULL) != 0ULL);                  \
        alive &= ~(sup_ | bb);                                                 \
      }                                                                        \
      KFVAR = kfacc;                                                           \
      if (kfacc) {                                                             \
        if ((kfacc >> lane) & 1ULL) {                                          \
          int idx = nkeep + __popcll(kfacc & ((1ULL << lane) - 1ULL));         \
          if (idx < 384) {                                                     \
            int K = (c << 8) + ((TT) << 6) + lane;                             \
            keepIdx[idx] = K;                                                  \
            keepA[idx] = packed_off(K) - (K >> 6);                             \
          }                                                                    \
        }                                                                      \
        nkeep += __popcll(kfacc);                                              \
        if (nkeep >= POST_NMS) done = true;                                    \
      }                                                                        \
    }

    RUN_WORD(or0, 0, ct00, 0ULL, kf0)
    RUN_WORD(or1, 1, ct11, (ct10 & kf0), kf1)
    RUN_WORD(or2, 2, ct22, (ct20 & kf0) | (ct21 & kf1), kf2)
    RUN_WORD(or3, 3, ct33, (ct30 & kf0) | (ct31 & kf1) | (ct32 & kf2), kf3)
#undef RUN_WORD
    (void)kf3;

    ct00 = n00; ct01 = n01; ct02 = n02; ct03 = n03;
    ct10 = n10; ct11 = n11; ct12 = n12; ct13 = n13;
    ct20 = n20; ct21 = n21; ct22 = n22; ct23 = n23;
    ct30 = n30; ct31 = n31; ct32 = n32; ct33 = n33;
  }
#undef COL_LOAD
  __syncthreads();

  for (int r = lane; r < POST_NMS; r += 64) {
    int kk = keepIdx[r];
    double4 b = sboxes[kk];
    float* o = out + r * 5;
    o[0] = 0.0f;
    o[1] = (float)b.x;
    o[2] = (float)b.y;
    o[3] = (float)b.z;
    o[4] = (float)b.w;
  }
}

extern "C" void kernel_launch(void* const* d_in, const int* in_sizes, int n_in,
                              void* d_out, int out_size, void* d_ws, size_t ws_size,
                              hipStream_t stream) {
  const float* cls = (const float*)d_in[0];
  const float* bbox = (const float*)d_in[1];
  const int* imh = (const int*)d_in[2];
  const int* imw = (const int*)d_in[3];
  float* out = (float*)d_out;

  // Workspace (2.67 MB total):
  // [0, 192512)          sboxes (6016 double4)
  // [192512, 385024)     colC   (6016 x 4 u64 column tiles)
  // [385024, 2670976)    packed upper-tri mask (285744 u64)
  //                      A/B key/val buffers (1.57MB) overlay the front of
  //                      the mask region (dead before k_mask runs).
  char* p = (char*)d_ws;
  double4* sboxes = (double4*)p;
  u64* colC = (u64*)(p + 192512);
  char* mb = p + 385024;
  u64* maskbuf = (u64*)mb;
  u64* Ak = (u64*)mb;                       // 65536 u64 (512 KB)
  u32* Av = (u32*)(mb + 524288);            // 65536 u32 (256 KB)
  u64* Bk = (u64*)(mb + 786432);            // 512 KB
  u32* Bv = (u32*)(mb + 1310720);           // 256 KB

  k_score_sort<<<64, 512, 0, stream>>>(cls, bbox, imh, imw, Ak, Av);
  k_merge1<<<NPAD / 256, 256, 0, stream>>>(Ak, Av, Bk, Bv);
  k_merge2<<<NPAD / 256, 256, 0, stream>>>(Bk, Bv, Ak, Av);
  k_merge3<<<(4 * CAP) / 256, 256, 0, stream>>>(Ak, Av, bbox, imh, imw, sboxes);
  k_mask<<<dim3(NBLK, NBLK), 64, 0, stream>>>(sboxes, maskbuf, colC);
  k_scan<<<1, 64, 0, stream>>>(maskbuf, colC, sboxes, out);
}

// Round 7
// 145.039 us; speedup vs baseline: 1.8832x; 1.0542x over previous
//
#include <hip/hip_runtime.h>

typedef unsigned long long u64;
typedef unsigned int u32;

#define FEAT_W 100
#define NANCH 9
#define NTOT 57600
#define NPAD 65536
#define PRE_NMS 6000
#define POST_NMS 300
#define NBLK 94        // 64-box blocks (mask words per full row)
#define NCHUNK 24      // 4 words (256 boxes) per k_scan iteration
#define CH_STRIDE 6400
#define CHUNK 1024
#define CAP 6144

__constant__ double c_base[9][4] = {
    {-84.0, -40.0, 99.0, 55.0},    {-176.0, -88.0, 191.0, 103.0},
    {-360.0, -184.0, 375.0, 199.0},{-56.0, -56.0, 71.0, 71.0},
    {-120.0, -120.0, 135.0, 135.0},{-248.0, -248.0, 263.0, 263.0},
    {-36.0, -80.0, 51.0, 95.0},    {-80.0, -168.0, 95.0, 183.0},
    {-168.0, -344.0, 183.0, 359.0}};

struct BoxD { double x1, y1, x2, y2; };

// Packed upper-triangular mask: row i stores words [i>>6, 94).
__device__ __forceinline__ int packed_off(int i) {
  int q = i >> 6, r = i & 63;
  return 94 * i - 32 * q * (q - 1) - r * q;
}

__device__ __forceinline__ BoxD decode_box(int i, const float* __restrict__ bbox,
                                           double imw1, double imh1) {
  int pos = i / NANCH;
  int a = i - pos * NANCH;
  int h = pos / FEAT_W;
  int w = pos - h * FEAT_W;
  double ax1 = c_base[a][0] + 16.0 * (double)w;
  double ay1 = c_base[a][1] + 16.0 * (double)h;
  double ax2 = c_base[a][2] + 16.0 * (double)w;
  double ay2 = c_base[a][3] + 16.0 * (double)h;
  double wd = ax2 - ax1 + 1.0;
  double hg = ay2 - ay1 + 1.0;
  double cx = ax1 + 0.5 * wd;
  double cy = ay1 + 0.5 * hg;
  const float* bp = bbox + (size_t)(4 * a) * CH_STRIDE + pos;
  double dx = (double)bp[0];
  double dy = (double)bp[CH_STRIDE];
  double dw = (double)bp[2 * CH_STRIDE];
  double dh = (double)bp[3 * CH_STRIDE];
  double pcx = dx * wd + cx;
  double pcy = dy * hg + cy;
  double pw = exp(dw) * wd;
  double ph = exp(dh) * hg;
  BoxD b;
  b.x1 = fmin(fmax(pcx - 0.5 * pw, 0.0), imw1);
  b.y1 = fmin(fmax(pcy - 0.5 * ph, 0.0), imh1);
  b.x2 = fmin(fmax(pcx + 0.5 * pw, 0.0), imw1);
  b.y2 = fmin(fmax(pcy + 0.5 * ph, 0.0), imh1);
  return b;
}

__device__ __forceinline__ u64 score_key(int i, const float* __restrict__ cls,
                                         const float* __restrict__ bbox,
                                         double imw1, double imh1) {
  BoxD b = decode_box(i, bbox, imw1, imh1);
  bool valid = (b.x2 - b.x1 + 1.0 >= 16.0) && (b.y2 - b.y1 + 1.0 >= 16.0);
  int pos = i / NANCH;
  int a = i - pos * NANCH;
  double c0 = (double)cls[(size_t)(2 * a) * CH_STRIDE + pos];
  double c1 = (double)cls[(size_t)(2 * a + 1) * CH_STRIDE + pos];
  double m = fmax(c0, c1);
  double e0 = exp(c0 - m), e1 = exp(c1 - m);
  double s = e1 / (e0 + e1);
  double masked = valid ? s : (double)(-1e30f);
  u64 u = (u64)__double_as_longlong(masked);
  return (u >> 63) ? ~u : (u | 0x8000000000000000ULL);
}

__device__ __forceinline__ bool before(u64 ka, u32 va, u64 kb, u32 vb) {
  return (ka > kb) || (ka == kb && va < vb);
}
__device__ __forceinline__ bool comes_after(u64 ka, u32 va, u64 kb, u32 vb) {
  return (ka < kb) || (ka == kb && va > vb);
}

// 64 blocks: compute 1024 keys, bitonic-sort in LDS, write chunk.
// v6: barriers only at cross-wave stages. For j <= 64, thread t = w*64+s
// touches only elements [w*128, w*128+128) (its wave's private span); wave
// lockstep + per-wave in-order LDS + may-alias program order make those
// stages barrier-free. Barrier needed at j >= 128 stages and on the
// transition out of one. 56 -> 11 barriers.
__global__ __launch_bounds__(512) void k_score_sort(
    const float* __restrict__ cls, const float* __restrict__ bbox,
    const int* __restrict__ imh, const int* __restrict__ imw,
    u64* __restrict__ keys, u32* __restrict__ vals) {
  __shared__ u64 sk[CHUNK];
  __shared__ u32 sv[CHUNK];
  int base = blockIdx.x * CHUNK;
  double imh1 = (double)(imh[0] - 1);
  double imw1 = (double)(imw[0] - 1);
  for (int t = threadIdx.x; t < CHUNK; t += 512) {
    int i = base + t;
    if (i < NTOT) { sk[t] = score_key(i, cls, bbox, imw1, imh1); sv[t] = (u32)i; }
    else { sk[t] = 0ULL; sv[t] = (u32)i; }
  }
  __syncthreads();
  bool prev_cross = false;
  for (int k = 2; k <= CHUNK; k <<= 1) {
    for (int j = k >> 1; j > 0; j >>= 1) {
      bool cross = (j >= 128);
      if (cross || prev_cross) __syncthreads();
      int t = threadIdx.x;
      int i = ((t & ~(j - 1)) << 1) | (t & (j - 1));
      int l = i | j;
      bool up = ((i & k) == 0);
      u64 ka = sk[i], kb = sk[l];
      u32 va = sv[i], vb = sv[l];
      if (comes_after(ka, va, kb, vb) == up) { sk[i] = kb; sv[i] = vb; sk[l] = ka; sv[l] = va; }
      prev_cross = cross;
    }
  }
  __syncthreads();
  for (int t = threadIdx.x; t < CHUNK; t += 512) { keys[base + t] = sk[t]; vals[base + t] = sv[t]; }
}

// Branchless sibling indices for 4-way merge: q = own slot, returns the
// three others in ascending order via i + (i >= q).
// v6 merges: the 3 binary searches are INTERLEAVED — per step, 3 independent
// (key,val) load pairs issue together, one latency wait. Dependent chain
// drops 3x (33 -> 11 loads for n=1024, 39 -> 13 for n=4096/6144).

// r1: 64 lists x1024 -> 16 x4096 (A -> B), 4-way rank-merge.
__global__ void k_merge1(const u64* __restrict__ Ak, const u32* __restrict__ Av,
                         u64* __restrict__ Bk, u32* __restrict__ Bv) {
  int gtid = blockIdx.x * blockDim.x + threadIdx.x;
  if (gtid >= NPAD) return;
  int lst = gtid >> 10, pos = gtid & 1023, grp = lst >> 2;
  u64 k = Ak[gtid]; u32 v = Av[gtid];
  int b0 = grp << 2;
  int q = lst & 3;
  int i0 = 0 + (0 >= q), i1 = 1 + (1 >= q), i2 = 2 + (2 >= q);
  const u64* K0 = Ak + (size_t)(b0 + i0) * 1024;
  const u64* K1 = Ak + (size_t)(b0 + i1) * 1024;
  const u64* K2 = Ak + (size_t)(b0 + i2) * 1024;
  const u32* V0 = Av + (size_t)(b0 + i0) * 1024;
  const u32* V1 = Av + (size_t)(b0 + i1) * 1024;
  const u32* V2 = Av + (size_t)(b0 + i2) * 1024;
  int lo0 = 0, hi0 = 1024, lo1 = 0, hi1 = 1024, lo2 = 0, hi2 = 1024;
  #pragma unroll
  for (int st = 0; st < 11; ++st) {
    int m0 = (lo0 + hi0) >> 1, m1 = (lo1 + hi1) >> 1, m2 = (lo2 + hi2) >> 1;
    int c0 = min(m0, 1023), c1 = min(m1, 1023), c2 = min(m2, 1023);
    u64 k0 = K0[c0], k1 = K1[c1], k2 = K2[c2];
    u32 v0 = V0[c0], v1 = V1[c1], v2 = V2[c2];
    if (lo0 < hi0) { if (before(k0, v0, k, v)) lo0 = m0 + 1; else hi0 = m0; }
    if (lo1 < hi1) { if (before(k1, v1, k, v)) lo1 = m1 + 1; else hi1 = m1; }
    if (lo2 < hi2) { if (before(k2, v2, k, v)) lo2 = m2 + 1; else hi2 = m2; }
  }
  int rank = pos + lo0 + lo1 + lo2;
  Bk[(size_t)grp * 4096 + rank] = k;
  Bv[(size_t)grp * 4096 + rank] = v;
}

// r2: 16 lists x4096 -> 4 x6144 (B -> A), truncated.
__global__ void k_merge2(const u64* __restrict__ Bk, const u32* __restrict__ Bv,
                         u64* __restrict__ Ak, u32* __restrict__ Av) {
  int gtid = blockIdx.x * blockDim.x + threadIdx.x;
  if (gtid >= NPAD) return;
  int lst = gtid >> 12, pos = gtid & 4095, grp = lst >> 2;
  u64 k = Bk[gtid]; u32 v = Bv[gtid];
  int b0 = grp << 2;
  int q = lst & 3;
  int i0 = 0 + (0 >= q), i1 = 1 + (1 >= q), i2 = 2 + (2 >= q);
  const u64* K0 = Bk + (size_t)(b0 + i0) * 4096;
  const u64* K1 = Bk + (size_t)(b0 + i1) * 4096;
  const u64* K2 = Bk + (size_t)(b0 + i2) * 4096;
  const u32* V0 = Bv + (size_t)(b0 + i0) * 4096;
  const u32* V1 = Bv + (size_t)(b0 + i1) * 4096;
  const u32* V2 = Bv + (size_t)(b0 + i2) * 4096;
  int lo0 = 0, hi0 = 4096, lo1 = 0, hi1 = 4096, lo2 = 0, hi2 = 4096;
  #pragma unroll
  for (int st = 0; st < 13; ++st) {
    int m0 = (lo0 + hi0) >> 1, m1 = (lo1 + hi1) >> 1, m2 = (lo2 + hi2) >> 1;
    int c0 = min(m0, 4095), c1 = min(m1, 4095), c2 = min(m2, 4095);
    u64 k0 = K0[c0], k1 = K1[c1], k2 = K2[c2];
    u32 v0 = V0[c0], v1 = V1[c1], v2 = V2[c2];
    if (lo0 < hi0) { if (before(k0, v0, k, v)) lo0 = m0 + 1; else hi0 = m0; }
    if (lo1 < hi1) { if (before(k1, v1, k, v)) lo1 = m1 + 1; else hi1 = m1; }
    if (lo2 < hi2) { if (before(k2, v2, k, v)) lo2 = m2 + 1; else hi2 = m2; }
  }
  int rank = pos + lo0 + lo1 + lo2;
  if (rank < CAP) { Ak[(size_t)grp * CAP + rank] = k; Av[(size_t)grp * CAP + rank] = v; }
}

// r3: 4 lists x6144 -> top-6000, fused with box decode into sboxes.
__global__ void k_merge3(const u64* __restrict__ Ak, const u32* __restrict__ Av,
                         const float* __restrict__ bbox, const int* __restrict__ imh,
                         const int* __restrict__ imw, double4* __restrict__ sboxes) {
  int gtid = blockIdx.x * blockDim.x + threadIdx.x;
  if (gtid >= 4 * CAP) return;
  int lst = gtid / CAP, pos = gtid - lst * CAP;
  u64 k = Ak[gtid]; u32 v = Av[gtid];
  int i0 = 0 + (0 >= lst), i1 = 1 + (1 >= lst), i2 = 2 + (2 >= lst);
  const u64* K0 = Ak + (size_t)i0 * CAP;
  const u64* K1 = Ak + (size_t)i1 * CAP;
  const u64* K2 = Ak + (size_t)i2 * CAP;
  const u32* V0 = Av + (size_t)i0 * CAP;
  const u32* V1 = Av + (size_t)i1 * CAP;
  const u32* V2 = Av + (size_t)i2 * CAP;
  int lo0 = 0, hi0 = CAP, lo1 = 0, hi1 = CAP, lo2 = 0, hi2 = CAP;
  #pragma unroll
  for (int st = 0; st < 13; ++st) {
    int m0 = (lo0 + hi0) >> 1, m1 = (lo1 + hi1) >> 1, m2 = (lo2 + hi2) >> 1;
    int c0 = min(m0, CAP - 1), c1 = min(m1, CAP - 1), c2 = min(m2, CAP - 1);
    u64 k0 = K0[c0], k1 = K1[c1], k2 = K2[c2];
    u32 v0 = V0[c0], v1 = V1[c1], v2 = V2[c2];
    if (lo0 < hi0) { if (before(k0, v0, k, v)) lo0 = m0 + 1; else hi0 = m0; }
    if (lo1 < hi1) { if (before(k1, v1, k, v)) lo1 = m1 + 1; else hi1 = m1; }
    if (lo2 < hi2) { if (before(k2, v2, k, v)) lo2 = m2 + 1; else hi2 = m2; }
  }
  int rank = pos + lo0 + lo1 + lo2;
  if (rank < PRE_NMS) {
    double imh1 = (double)(imh[0] - 1);
    double imw1 = (double)(imw[0] - 1);
    BoxD b = decode_box((int)v, bbox, imw1, imh1);
    sboxes[rank] = make_double4(b.x1, b.y1, b.x2, b.y2);
  }
}

// IoU mask, packed upper-tri rows + per-chunk column tiles (colC).
// Division-free IoU decision (inter > 0.7*union <=> iou > 0.7).
__global__ void k_mask(const double4* __restrict__ sboxes, u64* __restrict__ mask,
                       u64* __restrict__ colC) {
  __shared__ double4 cb[64];
  int bc = blockIdx.x, br = blockIdx.y;
  int t = threadIdx.x;
  bool samechunk = (bc >> 2) == (br >> 2);
  if (bc < br) {
    if (samechunk) colC[(size_t)(((bc << 6) + t) * 4 + (br & 3))] = 0;
    return;
  }
  int j0 = bc * 64;
  int jt = j0 + t;
  cb[t] = (jt < PRE_NMS) ? sboxes[jt] : make_double4(0.0, 0.0, 0.0, 0.0);
  __syncthreads();
  int i = br * 64 + t;
  u64 bits = 0;
  if (i < PRE_NMS) {
    double4 rb = sboxes[i];
    double areai = (rb.z - rb.x) * (rb.w - rb.y);
    int cmax = min(64, PRE_NMS - j0);
    for (int c = 0; c < cmax; ++c) {
      int j = j0 + c;
      if (j <= i) continue;
      double4 cbx = cb[c];
      double xx1 = fmax(rb.x, cbx.x), yy1 = fmax(rb.y, cbx.y);
      double xx2 = fmin(rb.z, cbx.z), yy2 = fmin(rb.w, cbx.w);
      double w = fmax(xx2 - xx1, 0.0), h = fmax(yy2 - yy1, 0.0);
      double inter = w * h;
      double areaj = (cbx.z - cbx.x) * (cbx.w - cbx.y);
      if (inter > 0.7 * (areai + areaj - inter)) bits |= (1ULL << c);
    }
    mask[(size_t)(packed_off(i) + (bc - br))] = bits;
  }
  if (samechunk) {
    u64 colbits = 0;
    for (int j2 = 0; j2 < 64; ++j2) {
      u64 bl = __ballot(((bits >> j2) & 1ULL) != 0);
      if (t == j2) colbits = bl;
    }
    colC[(size_t)(((bc << 6) + t) * 4 + (br & 3))] = colbits;
  }
}

__device__ __forceinline__ u64 valid_word(int w) {
  int base = w << 6;
  if (base >= PRE_NMS) return 0ULL;
  if (base + 64 <= PRE_NMS) return ~0ULL;
  return (1ULL << (PRE_NMS - base)) - 1ULL;
}

// Greedy NMS scan, single wave (v5 structure: 24 chunks, ballot suppression,
// deferred keep bookkeeping).
__global__ __launch_bounds__(64) void k_scan(const u64* __restrict__ mask,
                                             const u64* __restrict__ colC,
                                             const double4* __restrict__ sboxes,
                                             float* __restrict__ out) {
  __shared__ int keepIdx[384];
  __shared__ int keepA[384];
  int lane = threadIdx.x;
  for (int r = lane; r < 384; r += 64) { keepIdx[r] = 0; keepA[r] = 0; }
  int nkeep = 0;
  bool done = false;

  u64 ct00, ct01, ct02, ct03, ct10, ct11, ct12, ct13;
  u64 ct20, ct21, ct22, ct23, ct30, ct31, ct32, ct33;

#define COL_LOAD(cc, T, a0, a1, a2, a3)                                        \
  {                                                                            \
    int J_ = ((cc) << 8) + ((T) << 6) + lane;                                  \
    a0 = 0; a1 = 0; a2 = 0; a3 = 0;                                            \
    if (J_ < PRE_NMS) {                                                        \
      const ulonglong2* p_ = (const ulonglong2*)(colC + (size_t)J_ * 4);       \
      ulonglong2 x_ = p_[0], y_ = p_[1];                                       \
      a0 = x_.x; a1 = x_.y; a2 = y_.x; a3 = y_.y;                              \
    }                                                                          \
  }

  COL_LOAD(0, 0, ct00, ct01, ct02, ct03)
  COL_LOAD(0, 1, ct10, ct11, ct12, ct13)
  COL_LOAD(0, 2, ct20, ct21, ct22, ct23)
  COL_LOAD(0, 3, ct30, ct31, ct32, ct33)

  for (int c = 0; c < NCHUNK && !done; ++c) {
    int wbase = c << 2;
    bool tail_ok = (wbase + 2) < NBLK;

    u64 n00 = 0, n01 = 0, n02 = 0, n03 = 0, n10 = 0, n11 = 0, n12 = 0, n13 = 0;
    u64 n20 = 0, n21 = 0, n22 = 0, n23 = 0, n30 = 0, n31 = 0, n32 = 0, n33 = 0;
    if (c + 1 < NCHUNK) {
      COL_LOAD(c + 1, 0, n00, n01, n02, n03)
      COL_LOAD(c + 1, 1, n10, n11, n12, n13)
      COL_LOAD(c + 1, 2, n20, n21, n22, n23)
      COL_LOAD(c + 1, 3, n30, n31, n32, n33)
    }

    int nq = (nkeep + 63) >> 6;
    int a0 = keepA[lane], a1 = keepA[64 + lane], a2 = keepA[128 + lane];
    int a3 = keepA[192 + lane], a4 = keepA[256 + lane];
    u64 g00 = 0, g01 = 0, g02 = 0, g03 = 0;
    u64 g10 = 0, g11 = 0, g12 = 0, g13 = 0;
    u64 g20 = 0, g21 = 0, g22 = 0, g23 = 0;
    u64 g30 = 0, g31 = 0, g32 = 0, g33 = 0;
    u64 g40 = 0, g41 = 0, g42 = 0, g43 = 0;
#define GATHER(AA, x0, x1, x2, x3)                                             \
    {                                                                          \
      const u64* p_ = mask + (size_t)(AA) + wbase;                             \
      x0 = p_[0];                                                              \
      x1 = p_[1];                                                              \
      if (tail_ok) { x2 = p_[2]; x3 = p_[3]; }                                 \
    }
    if (nq > 0) GATHER(a0, g00, g01, g02, g03)
    if (nq > 1) GATHER(a1, g10, g11, g12, g13)
    if (nq > 2) GATHER(a2, g20, g21, g22, g23)
    if (nq > 3) GATHER(a3, g30, g31, g32, g33)
    if (nq > 4) GATHER(a4, g40, g41, g42, g43)
#undef GATHER
    u64 or0 = 0, or1 = 0, or2 = 0, or3 = 0;
    if (lane < nkeep)       { or0 |= g00; or1 |= g01; or2 |= g02; or3 |= g03; }
    if (64 + lane < nkeep)  { or0 |= g10; or1 |= g11; or2 |= g12; or3 |= g13; }
    if (128 + lane < nkeep) { or0 |= g20; or1 |= g21; or2 |= g22; or3 |= g23; }
    if (192 + lane < nkeep) { or0 |= g30; or1 |= g31; or2 |= g32; or3 |= g33; }
    if (256 + lane < nkeep) { or0 |= g40; or1 |= g41; or2 |= g42; or3 |= g43; }
    #pragma unroll
    for (int m = 32; m; m >>= 1) {
      or0 |= __shfl_xor(or0, m);
      or1 |= __shfl_xor(or1, m);
      or2 |= __shfl_xor(or2, m);
      or3 |= __shfl_xor(or3, m);
    }

    u64 kf0 = 0, kf1 = 0, kf2 = 0, kf3 = 0;

#define RUN_WORD(OR_, TT, DIAGC, CROSS_EXPR, KFVAR)                            \
    if (!done) {                                                               \
      u64 alive = ~(OR_) & valid_word(wbase + (TT));                           \
      alive &= ~__ballot((CROSS_EXPR) != 0ULL);                                \
      u64 kfacc = 0;                                                           \
      while (alive) {                                                          \
        int b = __builtin_ctzll(alive);                                        \
        u64 bb = 1ULL << b;                                                    \
        kfacc |= bb;                                                           \
        u64 sup_ = __ballot((((DIAGC) >> b) & 1ULL) != 0ULL);                  \
        alive &= ~(sup_ | bb);                                                 \
      }                                                                        \
      KFVAR = kfacc;                                                           \
      if (kfacc) {                                                             \
        if ((kfacc >> lane) & 1ULL) {                                          \
          int idx = nkeep + __popcll(kfacc & ((1ULL << lane) - 1ULL));         \
          if (idx < 384) {                                                     \
            int K = (c << 8) + ((TT) << 6) + lane;                             \
            keepIdx[idx] = K;                                                  \
            keepA[idx] = packed_off(K) - (K >> 6);                             \
          }                                                                    \
        }                                                                      \
        nkeep += __popcll(kfacc);                                              \
        if (nkeep >= POST_NMS) done = true;                                    \
      }                                                                        \
    }

    RUN_WORD(or0, 0, ct00, 0ULL, kf0)
    RUN_WORD(or1, 1, ct11, (ct10 & kf0), kf1)
    RUN_WORD(or2, 2, ct22, (ct20 & kf0) | (ct21 & kf1), kf2)
    RUN_WORD(or3, 3, ct33, (ct30 & kf0) | (ct31 & kf1) | (ct32 & kf2), kf3)
#undef RUN_WORD
    (void)kf3;

    ct00 = n00; ct01 = n01; ct02 = n02; ct03 = n03;
    ct10 = n10; ct11 = n11; ct12 = n12; ct13 = n13;
    ct20 = n20; ct21 = n21; ct22 = n22; ct23 = n23;
    ct30 = n30; ct31 = n31; ct32 = n32; ct33 = n33;
  }
#undef COL_LOAD
  __syncthreads();

  for (int r = lane; r < POST_NMS; r += 64) {
    int kk = keepIdx[r];
    double4 b = sboxes[kk];
    float* o = out + r * 5;
    o[0] = 0.0f;
    o[1] = (float)b.x;
    o[2] = (float)b.y;
    o[3] = (float)b.z;
    o[4] = (float)b.w;
  }
}

extern "C" void kernel_launch(void* const* d_in, const int* in_sizes, int n_in,
                              void* d_out, int out_size, void* d_ws, size_t ws_size,
                              hipStream_t stream) {
  const float* cls = (const float*)d_in[0];
  const float* bbox = (const float*)d_in[1];
  const int* imh = (const int*)d_in[2];
  const int* imw = (const int*)d_in[3];
  float* out = (float*)d_out;

  // Workspace (2.67 MB total):
  // [0, 192512)          sboxes (6016 double4)
  // [192512, 385024)     colC   (6016 x 4 u64 column tiles)
  // [385024, 2670976)    packed upper-tri mask (285744 u64)
  //                      A/B key/val buffers (1.57MB) overlay the front of
  //                      the mask region (dead before k_mask runs).
  char* p = (char*)d_ws;
  double4* sboxes = (double4*)p;
  u64* colC = (u64*)(p + 192512);
  char* mb = p + 385024;
  u64* maskbuf = (u64*)mb;
  u64* Ak = (u64*)mb;                       // 65536 u64 (512 KB)
  u32* Av = (u32*)(mb + 524288);            // 65536 u32 (256 KB)
  u64* Bk = (u64*)(mb + 786432);            // 512 KB
  u32* Bv = (u32*)(mb + 1310720);           // 256 KB

  k_score_sort<<<64, 512, 0, stream>>>(cls, bbox, imh, imw, Ak, Av);
  k_merge1<<<NPAD / 256, 256, 0, stream>>>(Ak, Av, Bk, Bv);
  k_merge2<<<NPAD / 256, 256, 0, stream>>>(Bk, Bv, Ak, Av);
  k_merge3<<<(4 * CAP) / 256, 256, 0, stream>>>(Ak, Av, bbox, imh, imw, sboxes);
  k_mask<<<dim3(NBLK, NBLK), 64, 0, stream>>>(sboxes, maskbuf, colC);
  k_scan<<<1, 64, 0, stream>>>(maskbuf, colC, sboxes, out);
}